// Round 14
// baseline (187.580 us; speedup 1.0000x reference)
//
#include <hip/hip_runtime.h>
#include <hip/hip_bf16.h>
#include <cstdint>
#include <cstddef>

// Problem constants
constexpr int Bc  = 4;
constexpr int Tc  = 2048;
constexpr int Dc  = 1024;
constexpr int Hc  = 16;
constexpr int DHc = 64;
constexpr int T2c = 1024;
constexpr int NCc = 32;          // chunks per (b,h) row; chunk = 64 timesteps
constexpr int NEXT = 1152;       // extended N for v-GEMM: 1024 v + 16 scores + 112 pad
constexpr int NT2  = 576;        // extended N for theta-GEMM: 512 theta + 1 mag + 63 pad
#define LN_EPS_F 1e-5f

typedef __attribute__((ext_vector_type(8))) short bf16x8;
typedef __attribute__((ext_vector_type(8))) ushort ushort8_t;
typedef __attribute__((ext_vector_type(4))) float f32x4;

__device__ inline ushort f2bf(float f) {
    union { float f; uint32_t u; } v; v.f = f;
    uint32_t r = v.u + 0x7FFFu + ((v.u >> 16) & 1u);   // RNE
    return (ushort)(r >> 16);
}
__device__ inline float bf2f(ushort u) {
    union { uint32_t u; float f; } v; v.u = ((uint32_t)u) << 16;
    return v.f;
}

__device__ inline void async_copy16(const void* g, void* lds) {
    __builtin_amdgcn_global_load_lds(
        (const __attribute__((address_space(1))) void*)g,
        (__attribute__((address_space(3))) void*)lds, 16, 0, 0);
}

// ---------------------------------------------------------------------------
// K0: fused prep (grid-partitioned):
//   [0, 8192)        x fp32 -> xb bf16
//   [.., +1024)      Wv -> WvXT rows 0..1023  ([n][k] bf16)
//   [.., +512)       Wt -> WtXT rows 0..511 scaled by g  + atomic u/w partials
//   [.., +64)        qk fold -> WvXT rows 1024..1039
//   [.., +56)        zero WvXT rows 1040..1151
//   [.., +4)         WtXT row 512 = g*Wm
//   [.., +32)        zero WtXT rows 513..575
//   [.., +1)         u[512] = sum g*Wm, w[512] = sum be*Wm
// (u/w and rowstats are zeroed by a hipMemsetAsync before this dispatch.)
// ---------------------------------------------------------------------------
constexpr int PREP_CVT  = 8192;
constexpr int PREP_WV   = PREP_CVT + 1024;       // 9216
constexpr int PREP_WT   = PREP_WV + 512;         // 9728
constexpr int PREP_QK   = PREP_WT + 64;          // 9792
constexpr int PREP_ZERO = PREP_QK + 56;          // 9848
constexpr int PREP_WMX  = PREP_ZERO + 4;         // 9852
constexpr int PREP_ZT   = PREP_WMX + 32;         // 9884
constexpr int PREP_MCOL = PREP_ZT + 1;           // 9885 (total blocks)

__global__ __launch_bounds__(256) void k_prep(const float* __restrict__ x,
                                              const float* __restrict__ Wv,
                                              const float* __restrict__ Wt,
                                              const float* __restrict__ Wk,
                                              const float* __restrict__ query,
                                              const float* __restrict__ g,
                                              const float* __restrict__ be,
                                              const float* __restrict__ Wm,
                                              ushort* __restrict__ xb,
                                              ushort* __restrict__ WvXT,
                                              ushort* __restrict__ WtXT,
                                              float* __restrict__ u,
                                              float* __restrict__ w) {
    __shared__ float tile[32][33];
    __shared__ float red2[512];
    int blk = blockIdx.x;
    int tid = threadIdx.x;
    if (blk < PREP_CVT) {
        int i = (blk * 256 + tid) * 4;
        float4 f = *(const float4*)(x + i);
        ushort4 o;
        o.x = f2bf(f.x); o.y = f2bf(f.y); o.z = f2bf(f.z); o.w = f2bf(f.w);
        *(ushort4*)(xb + i) = o;
    } else if (blk < PREP_WV) {
        int b2 = blk - PREP_CVT;
        int bx = b2 & 31, by = b2 >> 5;              // n-tile, k-tile
        int tx = tid & 31, ty = tid >> 5;
        #pragma unroll
        for (int r = 0; r < 32; r += 8)
            tile[ty + r][tx] = Wv[(size_t)(by * 32 + ty + r) * Dc + bx * 32 + tx];
        __syncthreads();
        #pragma unroll
        for (int r = 0; r < 32; r += 8)
            WvXT[(size_t)(bx * 32 + ty + r) * Dc + by * 32 + tx] = f2bf(tile[tx][ty + r]);
    } else if (blk < PREP_WT) {
        // Wt transpose, scaled by g[i]; also u/w column partials (atomic)
        int b2 = blk - PREP_WV;
        int bx = b2 & 15, by = b2 >> 4;              // n-tile (512), k-tile (1024)
        int tx = tid & 31, ty = tid >> 5;            // ty 0..7
        #pragma unroll
        for (int r = 0; r < 32; r += 8)
            tile[ty + r][tx] = Wt[(size_t)(by * 32 + ty + r) * (Dc / 2) + bx * 32 + tx];
        __syncthreads();
        #pragma unroll
        for (int r = 0; r < 32; r += 8)
            WtXT[(size_t)(bx * 32 + ty + r) * Dc + by * 32 + tx] =
                f2bf(tile[tx][ty + r] * g[by * 32 + tx]);
        float pu = 0.f, pw = 0.f;
        #pragma unroll
        for (int k = 0; k < 4; ++k) {
            int il = ty * 4 + k;                     // i_local
            float tv = tile[il][tx];                 // tile[i][c]
            pu += g[by * 32 + il] * tv;
            pw += be[by * 32 + il] * tv;
        }
        red2[ty * 32 + tx] = pu;
        red2[256 + ty * 32 + tx] = pw;
        __syncthreads();
        if (tid < 32) {
            float su = 0.f, sw = 0.f;
            #pragma unroll
            for (int q = 0; q < 8; ++q) { su += red2[q * 32 + tid]; sw += red2[256 + q * 32 + tid]; }
            atomicAdd(&u[bx * 32 + tid], su);
            atomicAdd(&w[bx * 32 + tid], sw);
        }
    } else if (blk < PREP_QK) {
        int idx = (blk - PREP_WT) * 256 + tid;       // 0..16383
        int h = idx >> 10, i = idx & (Dc - 1);
        const float* wrow = Wk + (size_t)i * Dc + h * DHc;
        const float* qh   = query + h * DHc;
        float s = 0.f;
        #pragma unroll 8
        for (int d = 0; d < DHc; ++d) s += wrow[d] * qh[d];
        WvXT[(size_t)(Dc + h) * Dc + i] = f2bf(s * 0.125f);
    } else if (blk < PREP_ZERO) {
        int idx = (blk - PREP_QK) * 256 + tid;       // zero WvXT rows 1040..1151
        uint4 z = {0, 0, 0, 0};
        *(uint4*)(WvXT + (size_t)1040 * Dc + idx * 8) = z;
    } else if (blk < PREP_WMX) {
        int idx = (blk - PREP_ZERO) * 256 + tid;     // 0..1023
        WtXT[(size_t)512 * Dc + idx] = f2bf(g[idx] * Wm[idx]);
    } else if (blk < PREP_ZT) {
        int idx = (blk - PREP_WMX) * 256 + tid;      // zero WtXT rows 513..575
        if (idx < 63 * Dc / 8) {
            uint4 z = {0, 0, 0, 0};
            *(uint4*)(WtXT + (size_t)513 * Dc + idx * 8) = z;
        }
    } else {
        // u[512] = sum g*Wm; w[512] = sum be*Wm
        int i = tid * 4;
        float4 gv  = *(const float4*)(g + i);
        float4 wmv = *(const float4*)(Wm + i);
        float4 bev = *(const float4*)(be + i);
        red2[tid]       = gv.x * wmv.x + gv.y * wmv.y + gv.z * wmv.z + gv.w * wmv.w;
        red2[256 + tid] = bev.x * wmv.x + bev.y * wmv.y + bev.z * wmv.z + bev.w * wmv.w;
        __syncthreads();
        for (int off = 128; off > 0; off >>= 1) {
            if (tid < off) { red2[tid] += red2[tid + off]; red2[256 + tid] += red2[256 + tid + off]; }
            __syncthreads();
        }
        if (tid == 0) { u[512] = red2[0]; w[512] = red2[256]; }
    }
}

// ---------------------------------------------------------------------------
// K4a: v-GEMM + scores.  BM=128, BN=64, BK=64, XOR-swizzled LDS (R10 shape).
//   grid (M/128=64 row-fastest for XCD, 17 col tiles) = 1088 blocks.
// ---------------------------------------------------------------------------
__global__ __launch_bounds__(256) void k_gemm_v(const ushort* __restrict__ A,
                                                const ushort* __restrict__ Bt,
                                                ushort* __restrict__ v,
                                                float* __restrict__ scores) {
    constexpr int K = Dc;
    __shared__ ushort As[128 * 64];                  // 16 KB
    __shared__ ushort Bs[64 * 64];                   // 8 KB
    int tid = threadIdx.x;
    int wid = tid >> 6, lane = tid & 63;
    int tile_m = blockIdx.x * 128, tile_n = blockIdx.y * 64;   // row fastest (XCD)
    int wm = wid >> 1, wn = wid & 1;                 // wave tile 64x32

    f32x4 acc[4][2] = {};

    int lrow = lane >> 3;                            // 0..7
    int lchunk = lane & 7;                           // 0..7 (16B chunk of 128B row)
    int schunk = lchunk ^ lrow;                      // swizzled source chunk
    int quad = lane >> 4, l15 = lane & 15;
    int sw = l15 & 7;

    for (int k0 = 0; k0 < K; k0 += 64) {
        #pragma unroll
        for (int r = 0; r < 4; ++r) {
            int rowgrp = wid * 4 + r;                // 0..15
            int row = rowgrp * 8 + lrow;
            async_copy16(A + (size_t)(tile_m + row) * K + k0 + schunk * 8,
                         &As[rowgrp * 8 * 64]);
        }
        #pragma unroll
        for (int r = 0; r < 2; ++r) {
            int rowgrp = wid * 2 + r;                // 0..7
            int row = rowgrp * 8 + lrow;
            async_copy16(Bt + (size_t)(tile_n + row) * K + k0 + schunk * 8,
                         &Bs[rowgrp * 8 * 64]);
        }
        __syncthreads();

        bf16x8 a_frag[4][2], b_frag[2][2];
        #pragma unroll
        for (int s = 0; s < 2; ++s) {
            int gc = s * 4 + quad;
            #pragma unroll
            for (int i = 0; i < 4; ++i)
                a_frag[i][s] = *(const bf16x8*)&As[(wm * 64 + i * 16 + l15) * 64 + ((gc ^ sw) * 8)];
            #pragma unroll
            for (int j = 0; j < 2; ++j)
                b_frag[j][s] = *(const bf16x8*)&Bs[(wn * 32 + j * 16 + l15) * 64 + ((gc ^ sw) * 8)];
        }
        #pragma unroll
        for (int s = 0; s < 2; ++s)
            #pragma unroll
            for (int i = 0; i < 4; ++i)
                #pragma unroll
                for (int j = 0; j < 2; ++j)
                    acc[i][j] = __builtin_amdgcn_mfma_f32_16x16x32_bf16(
                        a_frag[i][s], b_frag[j][s], acc[i][j], 0, 0, 0);
        __syncthreads();
    }

    #pragma unroll
    for (int j = 0; j < 2; ++j) {
        int col = tile_n + wn * 32 + j * 16 + l15;
        #pragma unroll
        for (int i = 0; i < 4; ++i) {
            #pragma unroll
            for (int r = 0; r < 4; ++r) {
                int row = tile_m + wm * 64 + i * 16 + quad * 4 + r;
                float val = acc[i][j][r];
                if (col < Dc) {
                    v[(size_t)row * Dc + col] = f2bf(val);
                } else if (col < Dc + Hc) {
                    int h = col - Dc;
                    int b2 = row >> 11, t = row & (Tc - 1);
                    scores[((size_t)b2 * Hc + h) * Tc + t] = val;
                }
            }
        }
    }
}

// ---------------------------------------------------------------------------
// K4b: theta+mag GEMM with algebraic LayerNorm epilogue.
//   B = WtXT (576 rows: g*Wt | g*Wm | pad), A = pooled (bf16, pre-LN).
//   theta[r,c] = rstd_r*(S1 - mu_r*u[c]) + w[c] + bt[c];  col 512 -> mag.
//   grid (M/128=32 row-fastest, 9 col tiles) = 288 blocks.
// ---------------------------------------------------------------------------
__global__ __launch_bounds__(256) void k_gemm_t(const ushort* __restrict__ A,
                                                const ushort* __restrict__ Bt,
                                                const float* __restrict__ u,
                                                const float* __restrict__ w,
                                                const float* __restrict__ bt,
                                                const float* __restrict__ bm,
                                                const float* __restrict__ rowsum,
                                                const float* __restrict__ rowsumsq,
                                                float* __restrict__ theta,
                                                float* __restrict__ mag) {
    constexpr int K = Dc;
    __shared__ ushort As[128 * 64];                  // 16 KB
    __shared__ ushort Bs[64 * 64];                   // 8 KB
    int tid = threadIdx.x;
    int wid = tid >> 6, lane = tid & 63;
    int tile_m = blockIdx.x * 128, tile_n = blockIdx.y * 64;   // row fastest (XCD)
    int wm = wid >> 1, wn = wid & 1;                 // wave tile 64x32

    f32x4 acc[4][2] = {};

    int lrow = lane >> 3;
    int lchunk = lane & 7;
    int schunk = lchunk ^ lrow;
    int quad = lane >> 4, l15 = lane & 15;
    int sw = l15 & 7;

    for (int k0 = 0; k0 < K; k0 += 64) {
        #pragma unroll
        for (int r = 0; r < 4; ++r) {
            int rowgrp = wid * 4 + r;                // 0..15
            int row = rowgrp * 8 + lrow;
            async_copy16(A + (size_t)(tile_m + row) * K + k0 + schunk * 8,
                         &As[rowgrp * 8 * 64]);
        }
        #pragma unroll
        for (int r = 0; r < 2; ++r) {
            int rowgrp = wid * 2 + r;                // 0..7
            int row = rowgrp * 8 + lrow;
            async_copy16(Bt + (size_t)(tile_n + row) * K + k0 + schunk * 8,
                         &Bs[rowgrp * 8 * 64]);
        }
        __syncthreads();

        bf16x8 a_frag[4][2], b_frag[2][2];
        #pragma unroll
        for (int s = 0; s < 2; ++s) {
            int gc = s * 4 + quad;
            #pragma unroll
            for (int i = 0; i < 4; ++i)
                a_frag[i][s] = *(const bf16x8*)&As[(wm * 64 + i * 16 + l15) * 64 + ((gc ^ sw) * 8)];
            #pragma unroll
            for (int j = 0; j < 2; ++j)
                b_frag[j][s] = *(const bf16x8*)&Bs[(wn * 32 + j * 16 + l15) * 64 + ((gc ^ sw) * 8)];
        }
        #pragma unroll
        for (int s = 0; s < 2; ++s)
            #pragma unroll
            for (int i = 0; i < 4; ++i)
                #pragma unroll
                for (int j = 0; j < 2; ++j)
                    acc[i][j] = __builtin_amdgcn_mfma_f32_16x16x32_bf16(
                        a_frag[i][s], b_frag[j][s], acc[i][j], 0, 0, 0);
        __syncthreads();
    }

    #pragma unroll
    for (int j = 0; j < 2; ++j) {
        int col = tile_n + wn * 32 + j * 16 + l15;
        float uc = (col <= Dc / 2) ? u[col] : 0.f;
        float wc = (col <= Dc / 2) ? w[col] : 0.f;
        #pragma unroll
        for (int i = 0; i < 4; ++i) {
            #pragma unroll
            for (int r = 0; r < 4; ++r) {
                int row = tile_m + wm * 64 + i * 16 + quad * 4 + r;
                float mu = rowsum[row] * (1.f / Dc);
                float rstd = rsqrtf(rowsumsq[row] * (1.f / Dc) - mu * mu + LN_EPS_F);
                float val = rstd * (acc[i][j][r] - mu * uc) + wc;
                if (col < Dc / 2) {
                    theta[(size_t)row * (Dc / 2) + col] = val + bt[col];
                } else if (col == Dc / 2) {
                    mag[row] = 1.f / (1.f + expf(-(val + bm[0])));
                }
            }
        }
    }
}

// ---------------------------------------------------------------------------
// K5a: per-chunk totals of E_t and E_t * v[t,h,:]  (shift-free softmax)
// ---------------------------------------------------------------------------
__global__ __launch_bounds__(64) void k_chunk(const float* __restrict__ scores,
                                              const ushort* __restrict__ v,
                                              float* __restrict__ chunkL,
                                              float* __restrict__ chunkAcc) {
    int idx = blockIdx.x;
    int c = idx & (NCc - 1);
    int bh = idx / NCc;
    int h = bh & (Hc - 1), b = bh / Hc;
    int lane = threadIdx.x;
    int tgrp = lane >> 3;
    int dgrp = lane & 7;
    int t0 = c * 64;
    const float* srow = scores + (size_t)bh * Tc + t0;
    const ushort* vbase = v + ((size_t)b * Tc + t0) * Dc + h * DHc + dgrp * 8;
    float acc[8] = {};
    float lsum = 0.f;
    #pragma unroll
    for (int it = 0; it < 8; ++it) {
        int t = it * 8 + tgrp;
        float e = expf(srow[t]);
        ushort8_t vv = *(const ushort8_t*)(vbase + (size_t)t * Dc);
        #pragma unroll
        for (int k = 0; k < 8; ++k) acc[k] += e * bf2f(vv[k]);
        lsum += e;
    }
    #pragma unroll
    for (int m = 8; m < 64; m <<= 1) {
        #pragma unroll
        for (int k = 0; k < 8; ++k) acc[k] += __shfl_xor(acc[k], m);
        lsum += __shfl_xor(lsum, m);
    }
    if (tgrp == 0) {
        float4 lo = {acc[0], acc[1], acc[2], acc[3]};
        float4 hi = {acc[4], acc[5], acc[6], acc[7]};
        *(float4*)&chunkAcc[(size_t)idx * DHc + dgrp * 8]     = lo;
        *(float4*)&chunkAcc[(size_t)idx * DHc + dgrp * 8 + 4] = hi;
        if (dgrp == 0) chunkL[idx] = lsum;
    }
}

// ---------------------------------------------------------------------------
// K5c: within-chunk scan + emit pooled (bf16) + per-row LN stats (atomics).
// ---------------------------------------------------------------------------
__global__ __launch_bounds__(64) void k_emit(const float* __restrict__ scores,
                                             const ushort* __restrict__ v,
                                             const float* __restrict__ chunkL,
                                             const float* __restrict__ chunkAcc,
                                             ushort* __restrict__ pooled,
                                             float* __restrict__ rowsum,
                                             float* __restrict__ rowsumsq) {
    int idx = blockIdx.x;
    int c = idx & (NCc - 1);
    int bh = idx / NCc;
    int h = bh & (Hc - 1), b = bh / Hc;
    int lane = threadIdx.x;
    int tgrp = lane >> 3, dgrp = lane & 7;
    int t0 = c * 64;
    __shared__ float E[64];
    __shared__ ushort vs[64 * DHc];
    E[lane] = expf(scores[(size_t)bh * Tc + t0 + lane]);
    const ushort* vbase = v + ((size_t)b * Tc + t0) * Dc + h * DHc + dgrp * 8;
    #pragma unroll
    for (int it = 0; it < 8; ++it) {
        int t = it * 8 + tgrp;
        *(ushort8_t*)&vs[t * DHc + dgrp * 8] = *(const ushort8_t*)(vbase + (size_t)t * Dc);
    }
    // inline exclusive prefix over chunks < c
    float acc = 0.f;
    for (int cc = 0; cc < c; ++cc)
        acc += chunkAcc[((size_t)bh * NCc + cc) * DHc + lane];
    float lP = (lane < c) ? chunkL[bh * NCc + lane] : 0.f;
    #pragma unroll
    for (int m = 1; m < 64; m <<= 1) lP += __shfl_xor(lP, m);
    float l = lP;
    __syncthreads();
    #pragma unroll 4
    for (int t = 0; t < 64; t += 2) {
        float e = E[t];
        acc += e * bf2f(vs[t * DHc + lane]);
        l += e;
        int j = (t0 + t) >> 1;
        float val = acc / l;
        pooled[((size_t)b * T2c + j) * Dc + h * DHc + lane] = f2bf(val);
        float s1 = val, s2 = val * val;
        #pragma unroll
        for (int m = 1; m < 64; m <<= 1) { s1 += __shfl_xor(s1, m); s2 += __shfl_xor(s2, m); }
        if (lane == 0) {
            atomicAdd(&rowsum[b * T2c + j], s1);
            atomicAdd(&rowsumsq[b * T2c + j], s2);
        }
        float e2 = E[t + 1];
        acc += e2 * bf2f(vs[(t + 1) * DHc + lane]);
        l += e2;
    }
}

// ---------------------------------------------------------------------------
extern "C" void kernel_launch(void* const* d_in, const int* in_sizes, int n_in,
                              void* d_out, int out_size, void* d_ws, size_t ws_size,
                              hipStream_t stream) {
    const float* x     = (const float*)d_in[0];
    const float* query = (const float*)d_in[1];
    const float* Wk    = (const float*)d_in[2];
    const float* Wv    = (const float*)d_in[3];
    const float* Wt    = (const float*)d_in[4];
    const float* bt    = (const float*)d_in[5];
    const float* Wm    = (const float*)d_in[6];
    const float* bm    = (const float*)d_in[7];
    const float* ln_g  = (const float*)d_in[8];
    const float* ln_b  = (const float*)d_in[9];
    float* out = (float*)d_out;

    // workspace layout. NO ALIASING (G16 hazard, hit in R3).
    char* w0 = (char*)d_ws;
    auto alloc = [&](size_t bytes) { char* p = w0; w0 += (bytes + 255) & ~(size_t)255; return p; };
    ushort* v        = (ushort*)alloc((size_t)Bc * Tc * Dc * 2);      // 16 MB
    ushort* pooled   = (ushort*)alloc((size_t)Bc * T2c * Dc * 2);     // 8 MB
    ushort* xb       = (ushort*)alloc((size_t)Bc * Tc * Dc * 2);      // 16 MB
    ushort* WvXT     = (ushort*)alloc((size_t)NEXT * Dc * 2);         // 2.25 MB
    ushort* WtXT     = (ushort*)alloc((size_t)NT2 * Dc * 2);          // 1.125 MB
    float*  scores   = (float*) alloc((size_t)Bc * Hc * Tc * 4);      // 512 KB
    float*  chunkL   = (float*) alloc((size_t)Bc * Hc * NCc * 4);
    float*  chunkAcc = (float*) alloc((size_t)Bc * Hc * NCc * DHc * 4);
    // zeroed-per-call region (single memset): rowsum, rowsumsq, u, w
    float*  rowsum   = (float*) alloc((size_t)Bc * T2c * 4);          // 16 KB
    float*  rowsumsq = (float*) alloc((size_t)Bc * T2c * 4);          // 16 KB
    float*  ucol     = (float*) alloc(520 * 4);
    float*  wcol     = (float*) alloc(520 * 4);
    size_t zbytes = (size_t)((char*)(wcol + 520) - (char*)rowsum);

    // 0) zero LN stats + column-correction accumulators
    hipMemsetAsync(rowsum, 0, zbytes, stream);
    // 1) fused prep: xb, WvXT (Wv + qk + pad), WtXT (g*Wt | g*Wm | pad), u/w
    k_prep<<<PREP_MCOL, 256, 0, stream>>>(x, Wv, Wt, Wk, query, ln_g, ln_b, Wm,
                                          xb, WvXT, WtXT, ucol, wcol);
    // 2) v + scores: BM=128 BN=64 BK=64 swizzled MFMA; grid (64, 17) = 1088.
    k_gemm_v<<<dim3((Bc * Tc) / 128, 17), 256, 0, stream>>>(xb, WvXT, v, scores);
    // 3) chunk totals
    k_chunk<<<Bc * Hc * NCc, 64, 0, stream>>>(scores, v, chunkL, chunkAcc);
    // 4) emit (inline prefix) + row stats
    k_emit<<<Bc * Hc * NCc, 64, 0, stream>>>(scores, v, chunkL, chunkAcc, pooled,
                                             rowsum, rowsumsq);
    // 5) theta + mag GEMM with algebraic-LN epilogue (grid 32 x 9)
    k_gemm_t<<<dim3((Bc * T2c) / 128, NT2 / 64), 256, 0, stream>>>(
        pooled, WtXT, ucol, wcol, bt, bm, rowsum, rowsumsq,
        out, out + (size_t)Bc * T2c * (Dc / 2));
}